// Round 2
// baseline (867.252 us; speedup 1.0000x reference)
//
#include <hip/hip_runtime.h>

#define KF   16
#define DIM  64
#define WPB  4
#define BLOCK (WPB * 64)

__device__ __forceinline__ float fsig(float x) {
    return __builtin_amdgcn_rcpf(1.0f + __expf(-x));
}
__device__ __forceinline__ float ftanh(float x) {
    float e = __expf(2.0f * x);
    return 1.0f - 2.0f * __builtin_amdgcn_rcpf(e + 1.0f);
}

__global__ __launch_bounds__(BLOCK, 5) void kgcn_kernel(
    const int* __restrict__ u, const int* __restrict__ v,
    const int* __restrict__ adj_ent, const int* __restrict__ adj_rel,
    const float* __restrict__ usr_emb, const float* __restrict__ rel_emb,
    const float* __restrict__ ent_emb, const float* __restrict__ W,
    const float* __restrict__ bias, float* __restrict__ out, int B)
{
    __shared__ float W_l[DIM * DIM];          // 16 KB, W[d][j] row-major
    __shared__ float b_l[DIM];
    __shared__ float urs_l[WPB][32];          // user . rel_emb[r]
    __shared__ int   e1l[WPB][KF];
    __shared__ float at1[WPB][KF];            // hop-0 attn (reused by layer 2)
    __shared__ int   e2l[WPB][KF * KF];
    __shared__ float at2[WPB][KF * KF];       // hop-1 attn
    __shared__ __align__(16) float xl[WPB][DIM];

    const int tid  = threadIdx.x;
    const int lane = tid & 63;
    const int w    = tid >> 6;

    // ---- block-level staging (W only; relT dropped -> +2 blocks/CU) ----
    for (int i = tid; i < DIM * DIM; i += BLOCK) W_l[i] = W[i];
    if (tid < DIM) b_l[tid] = bias[tid];
    __syncthreads();

    const int b = blockIdx.x * WPB + w;
    if (b >= B) return;

    // ---- user vector + hop-0 entity row (issue early) ----
    const float user  = usr_emb[(size_t)u[b] * DIM + lane];
    const int   e0    = v[b];
    const float ent0v = ent_emb[(size_t)e0 * DIM + lane];
    xl[w][lane] = user;

    // ---- urs[r] = user . rel_emb[r]; rel_emb is 8 KB -> L1-resident ----
    {
        const int r = lane & 31, h = lane >> 5;
        float s = 0.0f;
        #pragma unroll
        for (int dd = 0; dd < 32; ++dd) {
            const int d = h * 32 + dd;
            s += xl[w][d] * rel_emb[r * DIM + d];   // xl read is LDS broadcast
        }
        s += __shfl_xor(s, 32);
        if (lane < 32) urs_l[w][lane] = s;
    }

    // ---- adjacency expansion + raw scores ----
    if (lane < KF) {
        const int e1 = adj_ent[e0 * KF + lane];
        const int r1 = adj_rel[e0 * KF + lane];
        e1l[w][lane] = e1;
        at1[w][lane] = urs_l[w][r1];
    }
    #pragma unroll
    for (int it = 0; it < 4; ++it) {
        const int i = it * 64 + lane;         // 0..255
        const int m = i >> 4, k = i & 15;
        const int em = e1l[w][m];
        e2l[w][i] = adj_ent[em * KF + k];
        at2[w][i] = urs_l[w][adj_rel[em * KF + k]];
    }

    // ---- softmax over each contiguous 16-lane group ----
    #pragma unroll
    for (int it = 0; it < 4; ++it) {
        float s  = at2[w][it * 64 + lane];
        float mx = s;
        mx = fmaxf(mx, __shfl_xor(mx, 1));
        mx = fmaxf(mx, __shfl_xor(mx, 2));
        mx = fmaxf(mx, __shfl_xor(mx, 4));
        mx = fmaxf(mx, __shfl_xor(mx, 8));
        float e = __expf(s - mx);
        float sum = e;
        sum += __shfl_xor(sum, 1);
        sum += __shfl_xor(sum, 2);
        sum += __shfl_xor(sum, 4);
        sum += __shfl_xor(sum, 8);
        at2[w][it * 64 + lane] = e * __builtin_amdgcn_rcpf(sum);
    }
    {
        float s  = at1[w][lane & 15];
        float mx = s;
        mx = fmaxf(mx, __shfl_xor(mx, 1));
        mx = fmaxf(mx, __shfl_xor(mx, 2));
        mx = fmaxf(mx, __shfl_xor(mx, 4));
        mx = fmaxf(mx, __shfl_xor(mx, 8));
        float e = __expf(s - mx);
        float sum = e;
        sum += __shfl_xor(sum, 1);
        sum += __shfl_xor(sum, 2);
        sum += __shfl_xor(sum, 4);
        sum += __shfl_xor(sum, 8);
        if (lane < KF) at1[w][lane] = e * __builtin_amdgcn_rcpf(sum);
    }

    // ---- matvec: out[j] = bias[j] + sum_d x[d]*W[d][j]; 4 acc chains ----
    auto matvec = [&](float x) -> float {
        xl[w][lane] = x;
        float a0 = b_l[lane], a1 = 0.0f, a2 = 0.0f, a3 = 0.0f;
        #pragma unroll
        for (int d = 0; d < DIM; d += 16) {
            const float4 x0 = *(const float4*)&xl[w][d +  0];
            const float4 x1 = *(const float4*)&xl[w][d +  4];
            const float4 x2 = *(const float4*)&xl[w][d +  8];
            const float4 x3 = *(const float4*)&xl[w][d + 12];
            a0 = fmaf(x0.x, W_l[(d +  0) * DIM + lane], a0);
            a0 = fmaf(x0.y, W_l[(d +  1) * DIM + lane], a0);
            a0 = fmaf(x0.z, W_l[(d +  2) * DIM + lane], a0);
            a0 = fmaf(x0.w, W_l[(d +  3) * DIM + lane], a0);
            a1 = fmaf(x1.x, W_l[(d +  4) * DIM + lane], a1);
            a1 = fmaf(x1.y, W_l[(d +  5) * DIM + lane], a1);
            a1 = fmaf(x1.z, W_l[(d +  6) * DIM + lane], a1);
            a1 = fmaf(x1.w, W_l[(d +  7) * DIM + lane], a1);
            a2 = fmaf(x2.x, W_l[(d +  8) * DIM + lane], a2);
            a2 = fmaf(x2.y, W_l[(d +  9) * DIM + lane], a2);
            a2 = fmaf(x2.z, W_l[(d + 10) * DIM + lane], a2);
            a2 = fmaf(x2.w, W_l[(d + 11) * DIM + lane], a2);
            a3 = fmaf(x3.x, W_l[(d + 12) * DIM + lane], a3);
            a3 = fmaf(x3.y, W_l[(d + 13) * DIM + lane], a3);
            a3 = fmaf(x3.z, W_l[(d + 14) * DIM + lane], a3);
            a3 = fmaf(x3.w, W_l[(d + 15) * DIM + lane], a3);
        }
        return (a0 + a1) + (a2 + a3);
    };

    float agg2 = 0.0f;   // layer-2 aggregation: sum_m attn1[m]*h1[m]
    float agg0 = 0.0f;   // layer-1 hop-0 aggregation (folded; reuses self rows)

    // fetch ent rows for iteration m: 16 neighbors + the hop-1 self row
    auto fetch = [&](float (&buf)[KF + 1], int m) {
        #pragma unroll
        for (int k = 0; k < KF; ++k) {
            const int e = __builtin_amdgcn_readfirstlane(e2l[w][m * KF + k]);
            buf[k] = ent_emb[(size_t)e * DIM + lane];
        }
        const int es = __builtin_amdgcn_readfirstlane(e1l[w][m]);
        buf[KF] = ent_emb[(size_t)es * DIM + lane];
    };

    auto consume = [&](float (&buf)[KF + 1], int m) {
        float g0 = 0.0f, g1 = 0.0f, g2 = 0.0f, g3 = 0.0f;
        #pragma unroll
        for (int k = 0; k < KF; k += 4) {
            g0 = fmaf(at2[w][m * KF + k + 0], buf[k + 0], g0);
            g1 = fmaf(at2[w][m * KF + k + 1], buf[k + 1], g1);
            g2 = fmaf(at2[w][m * KF + k + 2], buf[k + 2], g2);
            g3 = fmaf(at2[w][m * KF + k + 3], buf[k + 3], g3);
        }
        const float at1m  = at1[w][m];
        const float selfv = buf[KF];
        const float x     = selfv + ((g0 + g1) + (g2 + g3));
        const float h1m   = fsig(matvec(x));
        agg2 = fmaf(at1m, h1m, agg2);
        agg0 = fmaf(at1m, selfv, agg0);
    };

    // ---- software-pipelined m-loop: fetch m+1 while computing m ----
    float bufA[KF + 1], bufB[KF + 1];
    fetch(bufA, 0);
    #pragma unroll 1
    for (int m = 0; m < KF; m += 2) {
        fetch(bufB, m + 1);
        consume(bufA, m);
        if (m + 2 < KF) fetch(bufA, m + 2);
        consume(bufB, m + 1);
    }

    // ---- layer-1 hop-0 + layer 2 (attn identical to at1) ----
    const float x0 = ent0v + agg0;
    const float h0 = fsig(matvec(x0));
    const float x2 = h0 + agg2;
    const float item = ftanh(matvec(x2));

    // ---- final dot + sigmoid ----
    float p = user * item;
    p += __shfl_xor(p, 1);
    p += __shfl_xor(p, 2);
    p += __shfl_xor(p, 4);
    p += __shfl_xor(p, 8);
    p += __shfl_xor(p, 16);
    p += __shfl_xor(p, 32);
    if (lane == 0) out[b] = fsig(p);
}

extern "C" void kernel_launch(void* const* d_in, const int* in_sizes, int n_in,
                              void* d_out, int out_size, void* d_ws, size_t ws_size,
                              hipStream_t stream) {
    const int*   u       = (const int*)d_in[0];
    const int*   v       = (const int*)d_in[1];
    const int*   adj_ent = (const int*)d_in[2];
    const int*   adj_rel = (const int*)d_in[3];
    const float* usr_emb = (const float*)d_in[4];
    const float* rel_emb = (const float*)d_in[5];
    const float* ent_emb = (const float*)d_in[6];
    const float* W       = (const float*)d_in[7];
    const float* bias    = (const float*)d_in[8];
    float* out = (float*)d_out;

    const int B = in_sizes[0];
    const int grid = (B + WPB - 1) / WPB;
    kgcn_kernel<<<grid, BLOCK, 0, stream>>>(u, v, adj_ent, adj_rel,
                                            usr_emb, rel_emb, ent_emb,
                                            W, bias, out, B);
}

// Round 3
// 211.053 us; speedup vs baseline: 4.1092x; 4.1092x over previous
//
#include <hip/hip_runtime.h>

#define KF    16
#define DIM   64
#define BLOCK 256   // 4 waves; one batch element per block; wave wv owns m = wv*4..wv*4+3

__device__ __forceinline__ float fsig(float x) {
    return __builtin_amdgcn_rcpf(1.0f + __expf(-x));
}
__device__ __forceinline__ float ftanh(float x) {
    float e = __expf(2.0f * x);
    return 1.0f - 2.0f * __builtin_amdgcn_rcpf(e + 1.0f);
}

__global__ __launch_bounds__(BLOCK) void kgcn_kernel(
    const int* __restrict__ u, const int* __restrict__ v,
    const int* __restrict__ adj_ent, const int* __restrict__ adj_rel,
    const float* __restrict__ usr_emb, const float* __restrict__ rel_emb,
    const float* __restrict__ ent_emb, const float* __restrict__ W,
    const float* __restrict__ bias, float* __restrict__ out, int B)
{
    __shared__ __align__(16) float W_l[DIM * DIM];   // 16 KB, W[d][j]
    __shared__ float b_l[DIM];
    __shared__ float urs_l[32];                      // user . rel_emb[r]
    __shared__ int   e1l[KF];
    __shared__ float at1l[KF];                       // hop-0 attn (== layer-2 attn)
    __shared__ int   e2l[4][64];                     // per-wave hop-1 indices
    __shared__ float at2l[4][64];                    // per-wave hop-1 attn
    __shared__ __align__(16) float xw[4][DIM];       // per-wave matvec broadcast buf
    __shared__ float part0[4][DIM];                  // per-wave agg0 partials
    __shared__ float part2[4][DIM];                  // per-wave agg2 partials

    const int tid  = threadIdx.x;
    const int lane = tid & 63;
    const int wv   = tid >> 6;
    const int b    = blockIdx.x;

    // ---- stage W (float4) + bias ----
    {
        const float4* W4  = (const float4*)W;
        float4*       Wl4 = (float4*)W_l;
        #pragma unroll
        for (int i = 0; i < 4; ++i) Wl4[tid + i * BLOCK] = W4[tid + i * BLOCK];
        if (tid < DIM) b_l[tid] = bias[tid];
    }

    const int e0 = v[b];
    float user = 0.0f, ent0v = 0.0f;

    if (wv == 0) {
        // user vector + hop-0 row
        user  = usr_emb[(size_t)u[b] * DIM + lane];
        ent0v = ent_emb[(size_t)e0 * DIM + lane];
        xw[0][lane] = user;
        // urs[r] = user . rel_emb[r]  (rel_emb is 8 KB, cache-resident)
        const int r = lane & 31, h = lane >> 5;
        float s = 0.0f;
        #pragma unroll
        for (int dd = 0; dd < 32; ++dd) {
            const int d = h * 32 + dd;
            s += xw[0][d] * rel_emb[r * DIM + d];
        }
        s += __shfl_xor(s, 32);
        if (lane < 32) urs_l[lane] = s;
        // hop-0 neighbors + at1 softmax (16-lane groups, redundant x4)
        const int k  = lane & 15;
        const int e1 = adj_ent[e0 * KF + k];
        const int r1 = adj_rel[e0 * KF + k];
        float sc = urs_l[r1];
        float mx = sc;
        mx = fmaxf(mx, __shfl_xor(mx, 1));
        mx = fmaxf(mx, __shfl_xor(mx, 2));
        mx = fmaxf(mx, __shfl_xor(mx, 4));
        mx = fmaxf(mx, __shfl_xor(mx, 8));
        float e  = __expf(sc - mx);
        float sm = e;
        sm += __shfl_xor(sm, 1);
        sm += __shfl_xor(sm, 2);
        sm += __shfl_xor(sm, 4);
        sm += __shfl_xor(sm, 8);
        if (lane < KF) { e1l[lane] = e1; at1l[lane] = e * __builtin_amdgcn_rcpf(sm); }
    }
    __syncthreads();

    // ---- per-wave hop-1 expansion + at2 softmax (lane = ml*16 + k) ----
    {
        const int ml = lane >> 4;
        const int kk = lane & 15;
        const int mm = wv * 4 + ml;
        const int em = e1l[mm];
        const int e2 = adj_ent[em * KF + kk];
        float sc = urs_l[adj_rel[em * KF + kk]];
        float mx = sc;
        mx = fmaxf(mx, __shfl_xor(mx, 1));
        mx = fmaxf(mx, __shfl_xor(mx, 2));
        mx = fmaxf(mx, __shfl_xor(mx, 4));
        mx = fmaxf(mx, __shfl_xor(mx, 8));
        float e  = __expf(sc - mx);
        float sm = e;
        sm += __shfl_xor(sm, 1);
        sm += __shfl_xor(sm, 2);
        sm += __shfl_xor(sm, 4);
        sm += __shfl_xor(sm, 8);
        e2l[wv][lane]  = e2;
        at2l[wv][lane] = e * __builtin_amdgcn_rcpf(sm);
    }

    // ---- matvec: out[j] = b[j] + sum_d x[d]*W[d][j]; lane=j; 4 acc chains ----
    auto matvec = [&](float x) -> float {
        xw[wv][lane] = x;
        float a0 = b_l[lane], a1 = 0.0f, a2 = 0.0f, a3 = 0.0f;
        #pragma unroll
        for (int d = 0; d < DIM; d += 16) {
            const float4 x0 = *(const float4*)&xw[wv][d +  0];
            const float4 x1 = *(const float4*)&xw[wv][d +  4];
            const float4 x2 = *(const float4*)&xw[wv][d +  8];
            const float4 x3 = *(const float4*)&xw[wv][d + 12];
            a0 = fmaf(x0.x, W_l[(d +  0) * DIM + lane], a0);
            a0 = fmaf(x0.y, W_l[(d +  1) * DIM + lane], a0);
            a0 = fmaf(x0.z, W_l[(d +  2) * DIM + lane], a0);
            a0 = fmaf(x0.w, W_l[(d +  3) * DIM + lane], a0);
            a1 = fmaf(x1.x, W_l[(d +  4) * DIM + lane], a1);
            a1 = fmaf(x1.y, W_l[(d +  5) * DIM + lane], a1);
            a1 = fmaf(x1.z, W_l[(d +  6) * DIM + lane], a1);
            a1 = fmaf(x1.w, W_l[(d +  7) * DIM + lane], a1);
            a2 = fmaf(x2.x, W_l[(d +  8) * DIM + lane], a2);
            a2 = fmaf(x2.y, W_l[(d +  9) * DIM + lane], a2);
            a2 = fmaf(x2.z, W_l[(d + 10) * DIM + lane], a2);
            a2 = fmaf(x2.w, W_l[(d + 11) * DIM + lane], a2);
            a3 = fmaf(x3.x, W_l[(d + 12) * DIM + lane], a3);
            a3 = fmaf(x3.y, W_l[(d + 13) * DIM + lane], a3);
            a3 = fmaf(x3.z, W_l[(d + 14) * DIM + lane], a3);
            a3 = fmaf(x3.w, W_l[(d + 15) * DIM + lane], a3);
        }
        return (a0 + a1) + (a2 + a3);
    };

    // ---- this wave's 4 hop-1 nodes ----
    float agg0p = 0.0f, agg2p = 0.0f;
    #pragma unroll 1
    for (int q = 0; q < 4; ++q) {
        const int m = wv * 4 + q;
        float rows[KF + 1];
        #pragma unroll
        for (int k = 0; k < KF; ++k) {
            const int e = __builtin_amdgcn_readfirstlane(e2l[wv][q * 16 + k]);
            rows[k] = ent_emb[(size_t)e * DIM + lane];
        }
        const int es = __builtin_amdgcn_readfirstlane(e1l[m]);
        rows[KF] = ent_emb[(size_t)es * DIM + lane];

        float g0 = 0.0f, g1 = 0.0f, g2 = 0.0f, g3 = 0.0f;
        #pragma unroll
        for (int k = 0; k < KF; k += 4) {
            g0 = fmaf(at2l[wv][q * 16 + k + 0], rows[k + 0], g0);
            g1 = fmaf(at2l[wv][q * 16 + k + 1], rows[k + 1], g1);
            g2 = fmaf(at2l[wv][q * 16 + k + 2], rows[k + 2], g2);
            g3 = fmaf(at2l[wv][q * 16 + k + 3], rows[k + 3], g3);
        }
        const float selfv = rows[KF];
        const float x     = selfv + ((g0 + g1) + (g2 + g3));
        const float h1m   = fsig(matvec(x));
        const float a1m   = at1l[m];
        agg2p = fmaf(a1m, h1m, agg2p);
        agg0p = fmaf(a1m, selfv, agg0p);
    }

    part0[wv][lane] = agg0p;
    part2[wv][lane] = agg2p;
    __syncthreads();

    // ---- tail: wave 0 combines partials, h0, item, dot ----
    if (wv == 0) {
        const float agg0 = (part0[0][lane] + part0[1][lane]) + (part0[2][lane] + part0[3][lane]);
        const float agg2 = (part2[0][lane] + part2[1][lane]) + (part2[2][lane] + part2[3][lane]);
        const float h0   = fsig(matvec(ent0v + agg0));
        const float item = ftanh(matvec(h0 + agg2));
        float p = user * item;
        p += __shfl_xor(p, 1);
        p += __shfl_xor(p, 2);
        p += __shfl_xor(p, 4);
        p += __shfl_xor(p, 8);
        p += __shfl_xor(p, 16);
        p += __shfl_xor(p, 32);
        if (lane == 0) out[b] = fsig(p);
    }
}

extern "C" void kernel_launch(void* const* d_in, const int* in_sizes, int n_in,
                              void* d_out, int out_size, void* d_ws, size_t ws_size,
                              hipStream_t stream) {
    const int*   u       = (const int*)d_in[0];
    const int*   v       = (const int*)d_in[1];
    const int*   adj_ent = (const int*)d_in[2];
    const int*   adj_rel = (const int*)d_in[3];
    const float* usr_emb = (const float*)d_in[4];
    const float* rel_emb = (const float*)d_in[5];
    const float* ent_emb = (const float*)d_in[6];
    const float* W       = (const float*)d_in[7];
    const float* bias    = (const float*)d_in[8];
    float* out = (float*)d_out;

    const int B = in_sizes[0];
    kgcn_kernel<<<B, BLOCK, 0, stream>>>(u, v, adj_ent, adj_rel,
                                         usr_emb, rel_emb, ent_emb,
                                         W, bias, out, B);
}

// Round 4
// 203.041 us; speedup vs baseline: 4.2713x; 1.0395x over previous
//
#include <hip/hip_runtime.h>

#define KF    16
#define DIM   64
#define BLOCK 256   // 4 waves; one batch element per block

typedef __attribute__((ext_vector_type(8))) short bs8;    // 8 bf16 (4 VGPRs)
typedef __attribute__((ext_vector_type(4))) float f32x4;  // MFMA accumulator

__device__ __forceinline__ float fsig(float x) {
    return __builtin_amdgcn_rcpf(1.0f + __expf(-x));
}
__device__ __forceinline__ float ftanh(float x) {
    float e = __expf(2.0f * x);
    return 1.0f - 2.0f * __builtin_amdgcn_rcpf(e + 1.0f);
}
__device__ __forceinline__ ushort f2bf(float x) {         // f32 -> bf16 bits, RNE
    uint u = __builtin_bit_cast(uint, x);
    u += 0x7fffu + ((u >> 16) & 1u);
    return (ushort)(u >> 16);
}

__global__ __launch_bounds__(BLOCK) void kgcn_kernel(
    const int* __restrict__ u, const int* __restrict__ v,
    const int* __restrict__ adj_ent, const int* __restrict__ adj_rel,
    const float* __restrict__ usr_emb, const float* __restrict__ rel_emb,
    const float* __restrict__ ent_emb, const float* __restrict__ W,
    const float* __restrict__ bias, float* __restrict__ out, int B)
{
    __shared__ float b_l[DIM];
    __shared__ float urs_l[32];                 // user . rel_emb[r]
    __shared__ int   e1l[KF];
    __shared__ float at1l[KF];                  // hop-0 attn (== layer-2 attn)
    __shared__ int   e2l[4][64];                // per-wave hop-1 indices
    __shared__ float at2l[4][64];               // per-wave hop-1 attn
    __shared__ __align__(16) ushort Xl[16][72]; // bf16 X rows, padded (+8) vs bank conflicts
    __shared__ float part0[4][DIM];             // per-wave agg0 partials
    __shared__ float xbuf[DIM];                 // user vector broadcast
    __shared__ float agg2s[DIM];                // sum_m at1[m]*h1[m]
    __shared__ float psum[4];

    const int tid  = threadIdx.x;
    const int lane = tid & 63;
    const int wv   = tid >> 6;
    const int b    = blockIdx.x;
    const int lr   = lane & 15;        // row (A) / col-in-tile (B,C)
    const int lg   = lane >> 4;        // k-group / row-group
    const int col  = wv * 16 + lr;     // this lane's output column

    // ---- W B-fragments for this wave's N-tile (one-time; W is 16 KB, cache-hot) ----
    // B[k][col]: lane holds k = lg*8+i (+32 for step 1)
    bs8 wf0, wf1;
    #pragma unroll
    for (int i = 0; i < 8; ++i) {
        const int k = lg * 8 + i;
        wf0[i] = (short)f2bf(W[k * DIM + col]);
        wf1[i] = (short)f2bf(W[(k + 32) * DIM + col]);
    }
    if (tid < DIM) b_l[tid] = bias[tid];

    const int e0 = v[b];
    float user = 0.0f, ent0v = 0.0f;

    if (wv == 0) {
        user  = usr_emb[(size_t)u[b] * DIM + lane];
        ent0v = ent_emb[(size_t)e0 * DIM + lane];
        xbuf[lane] = user;
        // urs[r] = user . rel_emb[r] (rel_emb 8 KB, cache-resident)
        const int r = lane & 31, h = lane >> 5;
        float s = 0.0f;
        #pragma unroll
        for (int dd = 0; dd < 32; ++dd) {
            const int d = h * 32 + dd;
            s += xbuf[d] * rel_emb[r * DIM + d];
        }
        s += __shfl_xor(s, 32);
        if (lane < 32) urs_l[lane] = s;
        // hop-0 neighbors + at1 softmax (16-lane groups, redundant x4)
        const int k  = lane & 15;
        const int e1 = adj_ent[e0 * KF + k];
        const int r1 = adj_rel[e0 * KF + k];
        float sc = urs_l[r1];
        float mx = sc;
        mx = fmaxf(mx, __shfl_xor(mx, 1));
        mx = fmaxf(mx, __shfl_xor(mx, 2));
        mx = fmaxf(mx, __shfl_xor(mx, 4));
        mx = fmaxf(mx, __shfl_xor(mx, 8));
        float e  = __expf(sc - mx);
        float sm = e;
        sm += __shfl_xor(sm, 1);
        sm += __shfl_xor(sm, 2);
        sm += __shfl_xor(sm, 4);
        sm += __shfl_xor(sm, 8);
        if (lane < KF) { e1l[lane] = e1; at1l[lane] = e * __builtin_amdgcn_rcpf(sm); }
    }
    __syncthreads();   // S0: urs_l, e1l, at1l, xbuf visible

    // ---- per-wave hop-1 expansion + at2 softmax (lane = lg*16 + lr over m-local) ----
    {
        const int mm = wv * 4 + lg;
        const int em = e1l[mm];
        const int e2 = adj_ent[em * KF + lr];
        float sc = urs_l[adj_rel[em * KF + lr]];
        float mx = sc;
        mx = fmaxf(mx, __shfl_xor(mx, 1));
        mx = fmaxf(mx, __shfl_xor(mx, 2));
        mx = fmaxf(mx, __shfl_xor(mx, 4));
        mx = fmaxf(mx, __shfl_xor(mx, 8));
        float e  = __expf(sc - mx);
        float sm = e;
        sm += __shfl_xor(sm, 1);
        sm += __shfl_xor(sm, 2);
        sm += __shfl_xor(sm, 4);
        sm += __shfl_xor(sm, 8);
        e2l[wv][lane]  = e2;
        at2l[wv][lane] = e * __builtin_amdgcn_rcpf(sm);
    }

    // ---- q-loop: gathers + aggregation only (no matvec); lane = d ----
    float agg0p = 0.0f;
    #pragma unroll 1
    for (int q = 0; q < 4; ++q) {
        const int m = wv * 4 + q;
        float rows[KF + 1];
        #pragma unroll
        for (int k = 0; k < KF; ++k) {
            const int e = __builtin_amdgcn_readfirstlane(e2l[wv][q * 16 + k]);
            rows[k] = ent_emb[(size_t)e * DIM + lane];
        }
        const int es = __builtin_amdgcn_readfirstlane(e1l[m]);
        rows[KF] = ent_emb[(size_t)es * DIM + lane];

        float g0 = 0.0f, g1 = 0.0f, g2 = 0.0f, g3 = 0.0f;
        #pragma unroll
        for (int k = 0; k < KF; k += 4) {
            g0 = fmaf(at2l[wv][q * 16 + k + 0], rows[k + 0], g0);
            g1 = fmaf(at2l[wv][q * 16 + k + 1], rows[k + 1], g1);
            g2 = fmaf(at2l[wv][q * 16 + k + 2], rows[k + 2], g2);
            g3 = fmaf(at2l[wv][q * 16 + k + 3], rows[k + 3], g3);
        }
        const float selfv = rows[KF];
        const float x     = selfv + ((g0 + g1) + (g2 + g3));
        agg0p = fmaf(at1l[m], selfv, agg0p);
        Xl[m][lane] = f2bf(x);
    }
    part0[wv][lane] = agg0p;
    __syncthreads();   // S1: X rows + part0 visible

    // ---- batched h1 matvecs: C = X @ W (+bias) for this wave's 16 cols ----
    const float bj = b_l[col];
    f32x4 c; c[0] = bj; c[1] = bj; c[2] = bj; c[3] = bj;
    {
        const ushort* arow = &Xl[lr][lg * 8];
        bs8 a0 = *(const bs8*)arow;          // k = lg*8..+7
        bs8 a1 = *(const bs8*)(arow + 32);   // k = 32 + lg*8..+7
        c = __builtin_amdgcn_mfma_f32_16x16x32_bf16(a0, wf0, c, 0, 0, 0);
        c = __builtin_amdgcn_mfma_f32_16x16x32_bf16(a1, wf1, c, 0, 0, 0);
    }
    {   // agg2[col] = sum_m at1[m] * sigmoid(C[m][col]); row m = lg*4 + r
        float p = 0.0f;
        #pragma unroll
        for (int r = 0; r < 4; ++r) p = fmaf(at1l[lg * 4 + r], fsig(c[r]), p);
        p += __shfl_xor(p, 16);
        p += __shfl_xor(p, 32);
        if (lane < 16) agg2s[col] = p;
    }
    __syncthreads();   // S2: agg2s ready; X reads complete

    // ---- x0 = ent0v + agg0 into X row 0 ----
    if (wv == 0) {
        const float agg0 = (part0[0][lane] + part0[1][lane]) + (part0[2][lane] + part0[3][lane]);
        Xl[0][lane] = f2bf(ent0v + agg0);
    }
    __syncthreads();   // S3

    // ---- h0 via MFMA (row 0 of C is the live row) ----
    c[0] = bj; c[1] = bj; c[2] = bj; c[3] = bj;
    {
        const ushort* arow = &Xl[lr][lg * 8];
        bs8 a0 = *(const bs8*)arow;
        bs8 a1 = *(const bs8*)(arow + 32);
        c = __builtin_amdgcn_mfma_f32_16x16x32_bf16(a0, wf0, c, 0, 0, 0);
        c = __builtin_amdgcn_mfma_f32_16x16x32_bf16(a1, wf1, c, 0, 0, 0);
    }
    __syncthreads();   // S4: A reads done before row-0 rewrite
    if (lane < 16) {                       // lg==0, reg 0 -> row 0
        const float h0 = fsig(c[0]);
        Xl[0][col] = f2bf(h0 + agg2s[col]);
    }
    __syncthreads();   // S5

    // ---- item via MFMA + final dot ----
    c[0] = bj; c[1] = bj; c[2] = bj; c[3] = bj;
    {
        const ushort* arow = &Xl[lr][lg * 8];
        bs8 a0 = *(const bs8*)arow;
        bs8 a1 = *(const bs8*)(arow + 32);
        c = __builtin_amdgcn_mfma_f32_16x16x32_bf16(a0, wf0, c, 0, 0, 0);
        c = __builtin_amdgcn_mfma_f32_16x16x32_bf16(a1, wf1, c, 0, 0, 0);
    }
    float pv = 0.0f;
    if (lane < 16) pv = xbuf[col] * ftanh(c[0]);
    pv += __shfl_xor(pv, 1);
    pv += __shfl_xor(pv, 2);
    pv += __shfl_xor(pv, 4);
    pv += __shfl_xor(pv, 8);
    pv += __shfl_xor(pv, 16);
    pv += __shfl_xor(pv, 32);
    if (lane == 0) psum[wv] = pv;
    __syncthreads();   // S6
    if (tid == 0) out[b] = fsig((psum[0] + psum[1]) + (psum[2] + psum[3]));
}

extern "C" void kernel_launch(void* const* d_in, const int* in_sizes, int n_in,
                              void* d_out, int out_size, void* d_ws, size_t ws_size,
                              hipStream_t stream) {
    const int*   u       = (const int*)d_in[0];
    const int*   v       = (const int*)d_in[1];
    const int*   adj_ent = (const int*)d_in[2];
    const int*   adj_rel = (const int*)d_in[3];
    const float* usr_emb = (const float*)d_in[4];
    const float* rel_emb = (const float*)d_in[5];
    const float* ent_emb = (const float*)d_in[6];
    const float* W       = (const float*)d_in[7];
    const float* bias    = (const float*)d_in[8];
    float* out = (float*)d_out;

    const int B = in_sizes[0];
    kgcn_kernel<<<B, BLOCK, 0, stream>>>(u, v, adj_ent, adj_rel,
                                         usr_emb, rel_emb, ent_emb,
                                         W, bias, out, B);
}

// Round 6
// 193.575 us; speedup vs baseline: 4.4802x; 1.0489x over previous
//
#include <hip/hip_runtime.h>

#define KF    16
#define DIM   64
#define BLOCK 256   // 4 waves; each wave owns one batch element

typedef __attribute__((ext_vector_type(8))) short bs8;    // 8 bf16 (4 VGPRs)
typedef __attribute__((ext_vector_type(4))) float f32x4;  // MFMA accumulator

// Compiler-only memory fence: pins LDS store/load program order against
// TBAA-driven reordering (ushort stores vs bs8 vector loads may be judged
// NoAlias). Zero instructions emitted.
#define C_FENCE() asm volatile("" ::: "memory")

__device__ __forceinline__ float fsig(float x) {
    return __builtin_amdgcn_rcpf(1.0f + __expf(-x));
}
__device__ __forceinline__ float ftanh(float x) {
    float e = __expf(2.0f * x);
    return 1.0f - 2.0f * __builtin_amdgcn_rcpf(e + 1.0f);
}
__device__ __forceinline__ ushort f2bf(float x) {         // f32 -> bf16 bits, RNE
    uint u = __builtin_bit_cast(uint, x);
    u += 0x7fffu + ((u >> 16) & 1u);
    return (ushort)(u >> 16);
}
__device__ __forceinline__ float rdlane_f(float v, int l) {
    return __builtin_bit_cast(float, __builtin_amdgcn_readlane(__builtin_bit_cast(int, v), l));
}

__global__ __launch_bounds__(BLOCK) void kgcn_kernel(
    const int* __restrict__ u, const int* __restrict__ v,
    const int* __restrict__ adj_ent, const int* __restrict__ adj_rel,
    const float* __restrict__ usr_emb, const float* __restrict__ rel_emb,
    const float* __restrict__ ent_emb, const float* __restrict__ W,
    const float* __restrict__ bias, float* __restrict__ out, int B)
{
    // W as bf16 MFMA B-fragments: [k-half][tile][lane][8] — lane-contiguous b128
    __shared__ __align__(16) ushort Wfrag[2][4][64][8];   // 8 KB
    // per-wave X rows, bf16, pitch 72
    __shared__ __align__(16) ushort Xl[4][16][72];        // 9 KB

    const int tid  = threadIdx.x;
    const int lane = tid & 63;
    const int wv   = tid >> 6;
    const int lr   = lane & 15;
    const int lg   = lane >> 4;

    // ---- stage W fragments (wave wv stages tile t = wv); one-time ----
    {
        const int col = wv * 16 + lr;
        bs8 p0, p1;
        #pragma unroll
        for (int i = 0; i < 8; ++i) {
            p0[i] = (short)f2bf(W[(lg * 8 + i) * DIM + col]);
            p1[i] = (short)f2bf(W[(lg * 8 + i + 32) * DIM + col]);
        }
        *(bs8*)&Wfrag[0][wv][lane][0] = p0;
        *(bs8*)&Wfrag[1][wv][lane][0] = p1;
    }
    const float biasr = bias[lane];
    __syncthreads();   // B0: Wfrag visible

    const int   b     = blockIdx.x * 4 + wv;
    const int   e0    = v[b];
    const float user  = usr_emb[(size_t)u[b] * DIM + lane];
    const float ent0v = ent_emb[(size_t)e0 * DIM + lane];

    // ---- urs[r] = user . rel_emb[r]; lane holds r = lane&31 (both halves) ----
    float ursr;
    {
        const int r  = lane & 31;
        const int hb = lane & 32;           // d = hb + dd
        float s = 0.0f;
        #pragma unroll
        for (int dd = 0; dd < 32; ++dd)
            s = fmaf(__shfl(user, hb + dd), rel_emb[r * DIM + hb + dd], s);
        s += __shfl_xor(s, 32);
        ursr = s;
    }

    // ---- hop-0: e1/at1 in regs (k = lr, 4 redundant copies) ----
    int e1r; float at1r;
    {
        e1r = adj_ent[e0 * KF + lr];
        const int r1 = adj_rel[e0 * KF + lr];
        float sc = __shfl(ursr, r1);
        float mx = sc;
        mx = fmaxf(mx, __shfl_xor(mx, 1));
        mx = fmaxf(mx, __shfl_xor(mx, 2));
        mx = fmaxf(mx, __shfl_xor(mx, 4));
        mx = fmaxf(mx, __shfl_xor(mx, 8));
        float e  = __expf(sc - mx);
        float sm = e;
        sm += __shfl_xor(sm, 1);
        sm += __shfl_xor(sm, 2);
        sm += __shfl_xor(sm, 4);
        sm += __shfl_xor(sm, 8);
        at1r = e * __builtin_amdgcn_rcpf(sm);
    }

    // ---- hop-1 expansion into regs: (m,k) -> reg it=m>>2, lane (m&3)*16+k ----
    int e2r[4]; float at2r[4];
    #pragma unroll
    for (int it = 0; it < 4; ++it) {
        const int m  = it * 4 + lg;         // entry (m, k=lr)
        const int em = __shfl(e1r, m);
        e2r[it] = adj_ent[em * KF + lr];
        const int r2 = adj_rel[em * KF + lr];
        float sc = __shfl(ursr, r2);
        float mx = sc;
        mx = fmaxf(mx, __shfl_xor(mx, 1));
        mx = fmaxf(mx, __shfl_xor(mx, 2));
        mx = fmaxf(mx, __shfl_xor(mx, 4));
        mx = fmaxf(mx, __shfl_xor(mx, 8));
        float e  = __expf(sc - mx);
        float sm = e;
        sm += __shfl_xor(sm, 1);
        sm += __shfl_xor(sm, 2);
        sm += __shfl_xor(sm, 4);
        sm += __shfl_xor(sm, 8);
        at2r[it] = e * __builtin_amdgcn_rcpf(sm);
    }

    // ---- q-loop: 16 nodes, 17 gathers each; indices via readlane ----
    float agg0p = 0.0f;
    #pragma unroll
    for (int qo = 0; qo < 4; ++qo) {        // static -> e2r/at2r statically indexed
        #pragma unroll 1
        for (int qi = 0; qi < 4; ++qi) {
            const int q = qo * 4 + qi;
            float rows[KF + 1];
            #pragma unroll
            for (int k = 0; k < KF; ++k) {
                const int e = __builtin_amdgcn_readlane(e2r[qo], qi * 16 + k);
                rows[k] = ent_emb[(size_t)e * DIM + lane];
            }
            const int es = __builtin_amdgcn_readlane(e1r, q);
            rows[KF] = ent_emb[(size_t)es * DIM + lane];

            float g0 = 0.0f, g1 = 0.0f, g2 = 0.0f, g3 = 0.0f;
            #pragma unroll
            for (int k = 0; k < KF; k += 4) {
                g0 = fmaf(rdlane_f(at2r[qo], qi * 16 + k + 0), rows[k + 0], g0);
                g1 = fmaf(rdlane_f(at2r[qo], qi * 16 + k + 1), rows[k + 1], g1);
                g2 = fmaf(rdlane_f(at2r[qo], qi * 16 + k + 2), rows[k + 2], g2);
                g3 = fmaf(rdlane_f(at2r[qo], qi * 16 + k + 3), rows[k + 3], g3);
            }
            const float selfv = rows[KF];
            agg0p = fmaf(rdlane_f(at1r, q), selfv, agg0p);
            Xl[wv][q][lane] = f2bf(selfv + ((g0 + g1) + (g2 + g3)));
        }
    }
    __syncthreads();   // B1: X rows committed before A-fragment reads

    // ---- per-tile bias ----
    float bj[4];
    #pragma unroll
    for (int t = 0; t < 4; ++t) bj[t] = __shfl(biasr, t * 16 + lr);

    // ---- P1: batched h1 = sig(X@W+b); agg2 per tile ----
    float agg2r[4];
    {
        const bs8 a0 = *(const bs8*)&Xl[wv][lr][lg * 8];
        const bs8 a1 = *(const bs8*)&Xl[wv][lr][lg * 8 + 32];
        #pragma unroll
        for (int t = 0; t < 4; ++t) {
            f32x4 c; c[0] = bj[t]; c[1] = bj[t]; c[2] = bj[t]; c[3] = bj[t];
            const bs8 w0 = *(const bs8*)&Wfrag[0][t][lane][0];
            const bs8 w1 = *(const bs8*)&Wfrag[1][t][lane][0];
            c = __builtin_amdgcn_mfma_f32_16x16x32_bf16(a0, w0, c, 0, 0, 0);
            c = __builtin_amdgcn_mfma_f32_16x16x32_bf16(a1, w1, c, 0, 0, 0);
            float p = 0.0f;                 // sum_m at1[m]*sig(C[m][col]); row = lg*4+r
            #pragma unroll
            for (int r = 0; r < 4; ++r)
                p = fmaf(__shfl(at1r, lg * 4 + r), fsig(c[r]), p);
            p += __shfl_xor(p, 16);
            p += __shfl_xor(p, 32);
            agg2r[t] = p;                   // valid all lanes for col = t*16+(lane&15)
        }
    }

    C_FENCE();                              // pin P1 loads BEFORE x0 store
    Xl[wv][0][lane] = f2bf(ent0v + agg0p);  // x0 into row 0
    __syncthreads();   // B2: x0 committed before P2 reads

    // ---- P2: h0 via MFMA on row 0 (rows 1-15 stale -> ignored) ----
    float x2v[4];
    {
        const bs8 a0 = *(const bs8*)&Xl[wv][lr][lg * 8];
        const bs8 a1 = *(const bs8*)&Xl[wv][lr][lg * 8 + 32];
        #pragma unroll
        for (int t = 0; t < 4; ++t) {
            f32x4 c; c[0] = bj[t]; c[1] = bj[t]; c[2] = bj[t]; c[3] = bj[t];
            const bs8 w0 = *(const bs8*)&Wfrag[0][t][lane][0];
            const bs8 w1 = *(const bs8*)&Wfrag[1][t][lane][0];
            c = __builtin_amdgcn_mfma_f32_16x16x32_bf16(a0, w0, c, 0, 0, 0);
            c = __builtin_amdgcn_mfma_f32_16x16x32_bf16(a1, w1, c, 0, 0, 0);
            x2v[t] = fsig(c[0]) + agg2r[t]; // meaningful at lanes<16 (row 0)
        }
    }

    C_FENCE();                              // pin P2 loads BEFORE x2 stores
    #pragma unroll
    for (int t = 0; t < 4; ++t)
        if (lane < 16) Xl[wv][0][t * 16 + lane] = f2bf(x2v[t]);
    __syncthreads();   // B3: x2 committed before P3 reads

    // ---- P3: item via MFMA + final dot ----
    float pv = 0.0f;
    {
        const bs8 a0 = *(const bs8*)&Xl[wv][lr][lg * 8];
        const bs8 a1 = *(const bs8*)&Xl[wv][lr][lg * 8 + 32];
        #pragma unroll
        for (int t = 0; t < 4; ++t) {
            f32x4 c; c[0] = bj[t]; c[1] = bj[t]; c[2] = bj[t]; c[3] = bj[t];
            const bs8 w0 = *(const bs8*)&Wfrag[0][t][lane][0];
            const bs8 w1 = *(const bs8*)&Wfrag[1][t][lane][0];
            c = __builtin_amdgcn_mfma_f32_16x16x32_bf16(a0, w0, c, 0, 0, 0);
            c = __builtin_amdgcn_mfma_f32_16x16x32_bf16(a1, w1, c, 0, 0, 0);
            const float uc = __shfl(user, t * 16 + lr);
            if (lane < 16) pv = fmaf(uc, ftanh(c[0]), pv);
        }
    }
    pv += __shfl_xor(pv, 1);
    pv += __shfl_xor(pv, 2);
    pv += __shfl_xor(pv, 4);
    pv += __shfl_xor(pv, 8);
    if (lane == 0) out[b] = fsig(pv);
}

extern "C" void kernel_launch(void* const* d_in, const int* in_sizes, int n_in,
                              void* d_out, int out_size, void* d_ws, size_t ws_size,
                              hipStream_t stream) {
    const int*   u       = (const int*)d_in[0];
    const int*   v       = (const int*)d_in[1];
    const int*   adj_ent = (const int*)d_in[2];
    const int*   adj_rel = (const int*)d_in[3];
    const float* usr_emb = (const float*)d_in[4];
    const float* rel_emb = (const float*)d_in[5];
    const float* ent_emb = (const float*)d_in[6];
    const float* W       = (const float*)d_in[7];
    const float* bias    = (const float*)d_in[8];
    float* out = (float*)d_out;

    const int B = in_sizes[0];
    kgcn_kernel<<<B / 4, BLOCK, 0, stream>>>(u, v, adj_ent, adj_rel,
                                             usr_emb, rel_emb, ent_emb,
                                             W, bias, out, B);
}

// Round 8
// 192.983 us; speedup vs baseline: 4.4939x; 1.0031x over previous
//
#include <hip/hip_runtime.h>

#define KF    16
#define DIM   64
#define BLOCK 256   // 4 waves; each wave owns one batch element; single barrier (W staging)

typedef __attribute__((ext_vector_type(8))) short bs8;    // 8 bf16 (4 VGPRs)
typedef __attribute__((ext_vector_type(4))) float f32x4;  // MFMA accumulator

// Compiler-order fence: pins LDS store/load program order (TBAA may judge
// ushort stores vs bs8 loads NoAlias). Same-wave DS ops execute in program
// order in HW, so no barrier/waitcnt is needed for a wave's own Xl slice.
#define C_FENCE() do { asm volatile("" ::: "memory"); \
                       __builtin_amdgcn_sched_barrier(0); } while (0)

__device__ __forceinline__ float fsig(float x) {
    return __builtin_amdgcn_rcpf(1.0f + __expf(-x));
}
__device__ __forceinline__ float ftanh(float x) {
    float e = __expf(2.0f * x);
    return 1.0f - 2.0f * __builtin_amdgcn_rcpf(e + 1.0f);
}
__device__ __forceinline__ ushort f2bf(float x) {         // f32 -> bf16 bits, RNE
    uint u = __builtin_bit_cast(uint, x);
    u += 0x7fffu + ((u >> 16) & 1u);
    return (ushort)(u >> 16);
}
__device__ __forceinline__ float rdlane_f(float v, int l) {
    return __builtin_bit_cast(float, __builtin_amdgcn_readlane(__builtin_bit_cast(int, v), l));
}

__global__ __launch_bounds__(BLOCK) void kgcn_kernel(
    const int* __restrict__ u, const int* __restrict__ v,
    const int* __restrict__ adj_ent, const int* __restrict__ adj_rel,
    const float* __restrict__ usr_emb, const float* __restrict__ rel_emb,
    const float* __restrict__ ent_emb, const float* __restrict__ W,
    const float* __restrict__ bias, float* __restrict__ out, int B)
{
    // W as bf16 MFMA B-fragments: [k-half][tile][lane][8] — lane-contiguous b128
    __shared__ __align__(16) ushort Wfrag[2][4][64][8];   // 8 KB
    // per-wave X rows, bf16, pitch 72
    __shared__ __align__(16) ushort Xl[4][16][72];        // 9 KB

    const int tid  = threadIdx.x;
    const int lane = tid & 63;
    const int wv   = tid >> 6;
    const int lr   = lane & 15;
    const int lg   = lane >> 4;

    // ---- stage W fragments (wave wv stages tile t = wv); one-time ----
    {
        const int col = wv * 16 + lr;
        bs8 p0, p1;
        #pragma unroll
        for (int i = 0; i < 8; ++i) {
            p0[i] = (short)f2bf(W[(lg * 8 + i) * DIM + col]);
            p1[i] = (short)f2bf(W[(lg * 8 + i + 32) * DIM + col]);
        }
        *(bs8*)&Wfrag[0][wv][lane][0] = p0;
        *(bs8*)&Wfrag[1][wv][lane][0] = p1;
    }
    const float biasr = bias[lane];
    __syncthreads();   // B0: Wfrag visible (the only block-wide barrier)

    const int   b     = blockIdx.x * 4 + wv;
    const int   e0    = v[b];
    const float user  = usr_emb[(size_t)u[b] * DIM + lane];
    const float ent0v = ent_emb[(size_t)e0 * DIM + lane];

    // ---- urs[r] = user . rel_emb[r]; lane holds r = lane&31 (both halves) ----
    float ursr;
    {
        const int r  = lane & 31;
        const int hb = lane & 32;           // d = hb + dd
        float s = 0.0f;
        #pragma unroll
        for (int dd = 0; dd < 32; ++dd)
            s = fmaf(__shfl(user, hb + dd), rel_emb[r * DIM + hb + dd], s);
        s += __shfl_xor(s, 32);
        ursr = s;
    }

    // ---- hop-0: e1/at1 in regs (k = lr, 4 redundant copies) ----
    int e1r; float at1r;
    {
        e1r = adj_ent[e0 * KF + lr];
        const int r1 = adj_rel[e0 * KF + lr];
        float sc = __shfl(ursr, r1);
        float mx = sc;
        mx = fmaxf(mx, __shfl_xor(mx, 1));
        mx = fmaxf(mx, __shfl_xor(mx, 2));
        mx = fmaxf(mx, __shfl_xor(mx, 4));
        mx = fmaxf(mx, __shfl_xor(mx, 8));
        float e  = __expf(sc - mx);
        float sm = e;
        sm += __shfl_xor(sm, 1);
        sm += __shfl_xor(sm, 2);
        sm += __shfl_xor(sm, 4);
        sm += __shfl_xor(sm, 8);
        at1r = e * __builtin_amdgcn_rcpf(sm);
    }

    // ---- hop-1 expansion into regs: (m,k) -> reg it=m>>2, lane (m&3)*16+k ----
    int e2r[4]; float at2r[4];
    #pragma unroll
    for (int it = 0; it < 4; ++it) {
        const int m  = it * 4 + lg;         // entry (m, k=lr)
        const int em = __shfl(e1r, m);
        e2r[it] = adj_ent[em * KF + lr];
        const int r2 = adj_rel[em * KF + lr];
        float sc = __shfl(ursr, r2);
        float mx = sc;
        mx = fmaxf(mx, __shfl_xor(mx, 1));
        mx = fmaxf(mx, __shfl_xor(mx, 2));
        mx = fmaxf(mx, __shfl_xor(mx, 4));
        mx = fmaxf(mx, __shfl_xor(mx, 8));
        float e  = __expf(sc - mx);
        float sm = e;
        sm += __shfl_xor(sm, 1);
        sm += __shfl_xor(sm, 2);
        sm += __shfl_xor(sm, 4);
        sm += __shfl_xor(sm, 8);
        at2r[it] = e * __builtin_amdgcn_rcpf(sm);
    }

    // ---- q-loop: 2-deep software pipeline, fully unrolled, static indices ----
    float agg0p = 0.0f;
    float bufA[KF + 1], bufB[KF + 1];

#define FETCH(BUF, Q) do {                                                      \
        _Pragma("unroll")                                                       \
        for (int k = 0; k < KF; ++k) {                                          \
            const int e = __builtin_amdgcn_readlane(e2r[(Q) >> 2],              \
                                                    ((Q) & 3) * 16 + k);        \
            BUF[k] = ent_emb[(size_t)e * DIM + lane];                           \
        }                                                                       \
        BUF[KF] = ent_emb[(size_t)__builtin_amdgcn_readlane(e1r, (Q)) * DIM     \
                          + lane];                                              \
    } while (0)

#define CONSUME(BUF, Q) do {                                                    \
        float g0 = 0.0f, g1 = 0.0f, g2 = 0.0f, g3 = 0.0f;                       \
        _Pragma("unroll")                                                       \
        for (int k = 0; k < KF; k += 4) {                                       \
            g0 = fmaf(rdlane_f(at2r[(Q) >> 2], ((Q) & 3) * 16 + k + 0), BUF[k + 0], g0); \
            g1 = fmaf(rdlane_f(at2r[(Q) >> 2], ((Q) & 3) * 16 + k + 1), BUF[k + 1], g1); \
            g2 = fmaf(rdlane_f(at2r[(Q) >> 2], ((Q) & 3) * 16 + k + 2), BUF[k + 2], g2); \
            g3 = fmaf(rdlane_f(at2r[(Q) >> 2], ((Q) & 3) * 16 + k + 3), BUF[k + 3], g3); \
        }                                                                       \
        agg0p = fmaf(rdlane_f(at1r, (Q)), BUF[KF], agg0p);                      \
        Xl[wv][(Q)][lane] = f2bf(BUF[KF] + ((g0 + g1) + (g2 + g3)));            \
    } while (0)

    FETCH(bufA, 0);
    FETCH(bufB, 1);   CONSUME(bufA, 0);
    FETCH(bufA, 2);   CONSUME(bufB, 1);
    FETCH(bufB, 3);   CONSUME(bufA, 2);
    FETCH(bufA, 4);   CONSUME(bufB, 3);
    FETCH(bufB, 5);   CONSUME(bufA, 4);
    FETCH(bufA, 6);   CONSUME(bufB, 5);
    FETCH(bufB, 7);   CONSUME(bufA, 6);
    FETCH(bufA, 8);   CONSUME(bufB, 7);
    FETCH(bufB, 9);   CONSUME(bufA, 8);
    FETCH(bufA, 10);  CONSUME(bufB, 9);
    FETCH(bufB, 11);  CONSUME(bufA, 10);
    FETCH(bufA, 12);  CONSUME(bufB, 11);
    FETCH(bufB, 13);  CONSUME(bufA, 12);
    FETCH(bufA, 14);  CONSUME(bufB, 13);
    FETCH(bufB, 15);  CONSUME(bufA, 14);
    CONSUME(bufB, 15);
#undef FETCH
#undef CONSUME

    C_FENCE();          // F1: X-row stores committed (program order) before P1 reads

    // ---- per-tile bias ----
    float bj[4];
    #pragma unroll
    for (int t = 0; t < 4; ++t) bj[t] = __shfl(biasr, t * 16 + lr);

    // ---- P1: batched h1 = sig(X@W+b); agg2 per tile ----
    float agg2r[4];
    {
        const bs8 a0 = *(const bs8*)&Xl[wv][lr][lg * 8];
        const bs8 a1 = *(const bs8*)&Xl[wv][lr][lg * 8 + 32];
        #pragma unroll
        for (int t = 0; t < 4; ++t) {
            f32x4 c; c[0] = bj[t]; c[1] = bj[t]; c[2] = bj[t]; c[3] = bj[t];
            const bs8 w0 = *(const bs8*)&Wfrag[0][t][lane][0];
            const bs8 w1 = *(const bs8*)&Wfrag[1][t][lane][0];
            c = __builtin_amdgcn_mfma_f32_16x16x32_bf16(a0, w0, c, 0, 0, 0);
            c = __builtin_amdgcn_mfma_f32_16x16x32_bf16(a1, w1, c, 0, 0, 0);
            float p = 0.0f;                 // sum_m at1[m]*sig(C[m][col]); row = lg*4+r
            #pragma unroll
            for (int r = 0; r < 4; ++r)
                p = fmaf(__shfl(at1r, lg * 4 + r), fsig(c[r]), p);
            p += __shfl_xor(p, 16);
            p += __shfl_xor(p, 32);
            agg2r[t] = p;                   // valid all lanes for col = t*16+(lane&15)
        }
    }

    C_FENCE();                              // F2: P1 loads BEFORE x0 store (WAR)
    Xl[wv][0][lane] = f2bf(ent0v + agg0p);  // x0 into row 0
    C_FENCE();                              // F3: x0 store before P2 reads (RAW)

    // ---- P2: h0 via MFMA on row 0 (rows 1-15 stale -> ignored) ----
    float x2v[4];
    {
        const bs8 a0 = *(const bs8*)&Xl[wv][lr][lg * 8];
        const bs8 a1 = *(const bs8*)&Xl[wv][lr][lg * 8 + 32];
        #pragma unroll
        for (int t = 0; t < 4; ++t) {
            f32x4 c; c[0] = bj[t]; c[1] = bj[t]; c[2] = bj[t]; c[3] = bj[t];
            const bs8 w0 = *(const bs8*)&Wfrag[0][t][lane][0];
            const bs8 w1 = *(const bs8*)&Wfrag[1][t][lane][0];
            c = __builtin_amdgcn_mfma_f32_16x16x32_bf16(a0, w0, c, 0, 0, 0);
            c = __builtin_amdgcn_mfma_f32_16x16x32_bf16(a1, w1, c, 0, 0, 0);
            x2v[t] = fsig(c[0]) + agg2r[t]; // meaningful at lanes<16 (row 0)
        }
    }

    C_FENCE();                              // F4: P2 loads BEFORE x2 stores (WAR)
    #pragma unroll
    for (int t = 0; t < 4; ++t)
        if (lane < 16) Xl[wv][0][t * 16 + lane] = f2bf(x2v[t]);
    C_FENCE();                              // F5: x2 stores before P3 reads (RAW)

    // ---- P3: item via MFMA + final dot ----
    float pv = 0.0f;
    {
        const bs8 a0 = *(const bs8*)&Xl[wv][lr][lg * 8];
        const bs8 a1 = *(const bs8*)&Xl[wv][lr][lg * 8 + 32];
        #pragma unroll
        for (int t = 0; t < 4; ++t) {
            f32x4 c; c[0] = bj[t]; c[1] = bj[t]; c[2] = bj[t]; c[3] = bj[t];
            const bs8 w0 = *(const bs8*)&Wfrag[0][t][lane][0];
            const bs8 w1 = *(const bs8*)&Wfrag[1][t][lane][0];
            c = __builtin_amdgcn_mfma_f32_16x16x32_bf16(a0, w0, c, 0, 0, 0);
            c = __builtin_amdgcn_mfma_f32_16x16x32_bf16(a1, w1, c, 0, 0, 0);
            const float uc = __shfl(user, t * 16 + lr);
            if (lane < 16) pv = fmaf(uc, ftanh(c[0]), pv);
        }
    }
    pv += __shfl_xor(pv, 1);
    pv += __shfl_xor(pv, 2);
    pv += __shfl_xor(pv, 4);
    pv += __shfl_xor(pv, 8);
    if (lane == 0) out[b] = fsig(pv);
}

extern "C" void kernel_launch(void* const* d_in, const int* in_sizes, int n_in,
                              void* d_out, int out_size, void* d_ws, size_t ws_size,
                              hipStream_t stream) {
    const int*   u       = (const int*)d_in[0];
    const int*   v       = (const int*)d_in[1];
    const int*   adj_ent = (const int*)d_in[2];
    const int*   adj_rel = (const int*)d_in[3];
    const float* usr_emb = (const float*)d_in[4];
    const float* rel_emb = (const float*)d_in[5];
    const float* ent_emb = (const float*)d_in[6];
    const float* W       = (const float*)d_in[7];
    const float* bias    = (const float*)d_in[8];
    float* out = (float*)d_out;

    const int B = in_sizes[0];
    kgcn_kernel<<<B / 4, BLOCK, 0, stream>>>(u, v, adj_ent, adj_rel,
                                             usr_emb, rel_emb, ent_emb,
                                             W, bias, out, B);
}